// Round 1
// baseline (890.996 us; speedup 1.0000x reference)
//
#include <hip/hip_runtime.h>

// ChebConv: B=4, N=4096, C_IN=C_OUT=128, K=3, fp32.
//   degree[b,n] = sum_m adj[b,m,n]
//   cheb(z) = lr*(degree*z - adj@z) - z,  lr = 2/(2+1e-6)
//   Z0=x, Z1=cheb(x), Z2=2*cheb(Z1)-Z0
//   out = view([B,K,N,C] -> [B,N,K*C]) @ W^T   (view SCRAMBLES: row n2 of the
//   flat [B][3*N*C] buffer is bytes [n2*384, n2*384+384) -> we materialize
//   Zflat=[Z0;Z1;Z2] per batch and GEMM the reinterpreted [4096 x 384]).
//
// Workspace layout (needs ~25.5 MB):
//   Zflat : 4 * 3*N*C floats  (25.2 MB)
//   deg   : 4 * N floats
//   Wt    : 384*128 floats (W transposed)

#define NN 4096
#define CF 128
#define NC (NN * CF)            // 524288
#define NC3 (3 * NC)
#define LRC 0.9999995f          // 2.0 / (2.0 + 1e-6)

__global__ __launch_bounds__(256) void degree_kernel(const float* __restrict__ adj,
                                                     float* __restrict__ deg) {
    // grid (4, 16, 4): 1024-col groups x 256-row slabs x batch
    const int b = blockIdx.z;
    const size_t base = (size_t)b * NN * NN;
    const int n0 = blockIdx.x * 1024;
    const int m0 = blockIdx.y * 256;
    const int t = threadIdx.x;
    float4 s = make_float4(0.f, 0.f, 0.f, 0.f);
    const size_t col = (size_t)(n0 + t * 4);
    for (int m = 0; m < 256; ++m) {
        const float4 v = *(const float4*)&adj[base + (size_t)(m0 + m) * NN + col];
        s.x += v.x; s.y += v.y; s.z += v.z; s.w += v.w;
    }
    float* dp = deg + b * NN + n0 + t * 4;
    atomicAdd(dp + 0, s.x);
    atomicAdd(dp + 1, s.y);
    atomicAdd(dp + 2, s.z);
    atomicAdd(dp + 3, s.w);
}

__global__ __launch_bounds__(256) void wt_kernel(const float* __restrict__ W,
                                                 float* __restrict__ Wt) {
    const int idx = blockIdx.x * 256 + threadIdx.x;   // < 128*384
    const int o = idx / 384;
    const int f = idx % 384;
    Wt[f * 128 + o] = W[idx];
}

// C = A[M x K] @ B[K x Ncols], 64x64 block tile, BK=16, 4x4 micro-tile.
// MODE 0: C = acc
// MODE 1: C = lr*(deg[m]*x - acc) - x               (Z1 = cheb(x))
// MODE 2: C = 2*(lr*(deg[m]*z - acc) - z) - x       (Z2 = 2*cheb(Z1) - Z0)
template <int MODE>
__global__ __launch_bounds__(256) void gemm_cheb(
    const float* __restrict__ A, size_t sA, int lda,
    const float* __restrict__ Bmat, size_t sB, int ldb,
    float* __restrict__ Cmat, size_t sC, int ldc,
    int Kdim,
    const float* __restrict__ deg,
    const float* __restrict__ xin,
    const float* __restrict__ zin, size_t sZ)
{
    const int b = blockIdx.z;
    const float* Ab = A + (size_t)b * sA;
    const float* Bb = Bmat + (size_t)b * sB;
    float* Cb = Cmat + (size_t)b * sC;

    const int t = threadIdx.x;
    const int tx = t & 15, ty = t >> 4;
    const int m0 = blockIdx.y * 64, n0 = blockIdx.x * 64;

    __shared__ float As[16][68];   // As[k][m], +4 pad keeps b128 reads aligned, <=2-way banks
    __shared__ float Bs[16][64];   // Bs[k][n]

    const int arow = t >> 2;          // 0..63
    const int ak4  = (t & 3) << 2;    // 0,4,8,12
    const int bk   = t >> 4;          // 0..15
    const int bn4  = (t & 15) << 2;   // 0..60

    float4 acc[4];
    acc[0] = acc[1] = acc[2] = acc[3] = make_float4(0.f, 0.f, 0.f, 0.f);

    const float* aptr = Ab + (size_t)(m0 + arow) * lda + ak4;
    const float* bptr = Bb + (size_t)bk * ldb + n0 + bn4;

    // software prefetch: next tile's global loads issued before compute
    float4 av = *(const float4*)aptr;
    float4 bv = *(const float4*)bptr;

    for (int k0 = 0; k0 < Kdim; k0 += 16) {
        __syncthreads();
        As[ak4 + 0][arow] = av.x;
        As[ak4 + 1][arow] = av.y;
        As[ak4 + 2][arow] = av.z;
        As[ak4 + 3][arow] = av.w;
        *(float4*)&Bs[bk][bn4] = bv;
        __syncthreads();
        if (k0 + 16 < Kdim) {
            av = *(const float4*)(aptr + k0 + 16);
            bv = *(const float4*)(bptr + (size_t)(k0 + 16) * ldb);
        }
#pragma unroll
        for (int kk = 0; kk < 16; ++kk) {
            const float4 a  = *(const float4*)&As[kk][ty << 2];
            const float4 bb = *(const float4*)&Bs[kk][tx << 2];
            acc[0].x += a.x * bb.x; acc[0].y += a.x * bb.y; acc[0].z += a.x * bb.z; acc[0].w += a.x * bb.w;
            acc[1].x += a.y * bb.x; acc[1].y += a.y * bb.y; acc[1].z += a.y * bb.z; acc[1].w += a.y * bb.w;
            acc[2].x += a.z * bb.x; acc[2].y += a.z * bb.y; acc[2].z += a.z * bb.z; acc[2].w += a.z * bb.w;
            acc[3].x += a.w * bb.x; acc[3].y += a.w * bb.y; acc[3].z += a.w * bb.z; acc[3].w += a.w * bb.w;
        }
    }

    const int ncol = n0 + (tx << 2);
#pragma unroll
    for (int i = 0; i < 4; ++i) {
        const int m = m0 + (ty << 2) + i;
        float4 r = acc[i];
        if (MODE == 1) {
            const float d = deg[b * NN + m];
            const float4 xv = *(const float4*)&xin[(size_t)b * NC + (size_t)m * CF + ncol];
            r.x = LRC * (d * xv.x - r.x) - xv.x;
            r.y = LRC * (d * xv.y - r.y) - xv.y;
            r.z = LRC * (d * xv.z - r.z) - xv.z;
            r.w = LRC * (d * xv.w - r.w) - xv.w;
        } else if (MODE == 2) {
            const float d = deg[b * NN + m];
            const float4 xv = *(const float4*)&xin[(size_t)b * NC + (size_t)m * CF + ncol];
            const float4 zv = *(const float4*)&zin[(size_t)b * sZ + (size_t)m * CF + ncol];
            r.x = 2.f * (LRC * (d * zv.x - r.x) - zv.x) - xv.x;
            r.y = 2.f * (LRC * (d * zv.y - r.y) - zv.y) - xv.y;
            r.z = 2.f * (LRC * (d * zv.z - r.z) - zv.z) - xv.z;
            r.w = 2.f * (LRC * (d * zv.w - r.w) - zv.w) - xv.w;
        }
        *(float4*)&Cb[(size_t)m * ldc + ncol] = r;
    }
}

extern "C" void kernel_launch(void* const* d_in, const int* in_sizes, int n_in,
                              void* d_out, int out_size, void* d_ws, size_t ws_size,
                              hipStream_t stream) {
    const float* x   = (const float*)d_in[0];   // [4, 4096, 128]
    const float* adj = (const float*)d_in[1];   // [4, 4096, 4096]
    const float* W   = (const float*)d_in[2];   // [128, 384]
    float* out = (float*)d_out;                 // [4, 4096, 128]

    char* ws = (char*)d_ws;
    float* Zflat = (float*)ws;                                    // 4 * 3*N*C floats
    float* deg   = (float*)(ws + (size_t)4 * NC3 * sizeof(float));
    float* Wt    = deg + 4 * NN;

    hipMemsetAsync(deg, 0, 4 * NN * sizeof(float), stream);
    degree_kernel<<<dim3(4, 16, 4), 256, 0, stream>>>(adj, deg);

    // Z0 = x into the flat buffer (per-batch chunk 0)
    for (int b = 0; b < 4; ++b)
        hipMemcpyAsync(Zflat + (size_t)b * NC3, x + (size_t)b * NC,
                       NC * sizeof(float), hipMemcpyDeviceToDevice, stream);

    wt_kernel<<<dim3(192), 256, 0, stream>>>(W, Wt);

    // Z1 = cheb(x)
    gemm_cheb<1><<<dim3(2, 64, 4), 256, 0, stream>>>(
        adj, (size_t)NN * NN, NN,
        x, NC, CF,
        Zflat + NC, NC3, CF,
        NN,
        deg, x, nullptr, 0);

    // Z2 = 2*cheb(Z1) - x
    gemm_cheb<2><<<dim3(2, 64, 4), 256, 0, stream>>>(
        adj, (size_t)NN * NN, NN,
        Zflat + NC, NC3, CF,
        Zflat + 2 * NC, NC3, CF,
        NN,
        deg, x, Zflat + NC, NC3);

    // out[b] = Zflat[b] (viewed [4096 x 384]) @ Wt
    gemm_cheb<0><<<dim3(2, 64, 4), 256, 0, stream>>>(
        Zflat, NC3, 3 * CF,
        Wt, 0, CF,
        out, NC, CF,
        384,
        nullptr, nullptr, nullptr, 0);
}

// Round 2
// 587.007 us; speedup vs baseline: 1.5179x; 1.5179x over previous
//
#include <hip/hip_runtime.h>

// ChebConv B=4, N=4096, C=128, K=3 fp32.
// Round 2: the two adj@z GEMMs -> bf16 MFMA (16x16x32), fp32 elementwise epilogue.
//   - adj used as MFMA A-operand (row-major). Staged to LDS (XOR-swizzled, dbuf).
//   - z used as B-operand from a TRANSPOSED bf16 buffer zT[128][4096] (L2-resident),
//     B-fragments loaded directly from global (k-contiguous 16B).
//   - deg*z - acc epilogue in fp32 (dominant term exact -> bf16 error negligible).
//   - final scrambled-view GEMM stays fp32 vector (proven, ~26us).
// ws layout: Zflat fp32 25.2MB | xTb 4MB | z1Tb 4MB | deg 64KB | Wt 192KB | [adjB 128MB if ws allows]

#define NN 4096
#define CF 128
#define NC (NN * CF)
#define NC3 (3 * NC)
#define LRC 0.9999995f

typedef __attribute__((ext_vector_type(8))) short bf16x8;
typedef __attribute__((ext_vector_type(4))) float f32x4;

__device__ __forceinline__ unsigned short f2b(float f) {
    unsigned u = __float_as_uint(f);
    return (unsigned short)((u + 0x7FFFu + ((u >> 16) & 1u)) >> 16);  // RNE
}

// ---- degree only (no-cast path) ----
__global__ __launch_bounds__(256) void degree_kernel(const float* __restrict__ adj,
                                                     float* __restrict__ deg) {
    const int b = blockIdx.z;
    const size_t base = (size_t)b * NN * NN;
    const int n0 = blockIdx.x * 1024;
    const int m0 = blockIdx.y * 256;
    const int t = threadIdx.x;
    float4 s = make_float4(0.f, 0.f, 0.f, 0.f);
    const size_t col = (size_t)(n0 + t * 4);
    for (int m = 0; m < 256; ++m) {
        const float4 v = *(const float4*)&adj[base + (size_t)(m0 + m) * NN + col];
        s.x += v.x; s.y += v.y; s.z += v.z; s.w += v.w;
    }
    float* dp = deg + b * NN + n0 + t * 4;
    atomicAdd(dp + 0, s.x);
    atomicAdd(dp + 1, s.y);
    atomicAdd(dp + 2, s.z);
    atomicAdd(dp + 3, s.w);
}

// ---- degree + adj->bf16 cast (cast path, one pass over fp32 adj) ----
__global__ __launch_bounds__(256) void prep_cast(const float* __restrict__ adj,
                                                 unsigned short* __restrict__ adjB,
                                                 float* __restrict__ deg) {
    const int b = blockIdx.z;
    const size_t base = (size_t)b * NN * NN;
    const int n0 = blockIdx.x * 1024;
    const int m0 = blockIdx.y * 256;
    const int t = threadIdx.x;
    float4 s = make_float4(0.f, 0.f, 0.f, 0.f);
    const size_t col = (size_t)(n0 + t * 4);
    for (int m = 0; m < 256; ++m) {
        const size_t idx = base + (size_t)(m0 + m) * NN + col;
        const float4 v = *(const float4*)&adj[idx];
        s.x += v.x; s.y += v.y; s.z += v.z; s.w += v.w;
        ushort4 o;
        o.x = f2b(v.x); o.y = f2b(v.y); o.z = f2b(v.z); o.w = f2b(v.w);
        *(ushort4*)&adjB[idx] = o;
    }
    float* dp = deg + b * NN + n0 + t * 4;
    atomicAdd(dp + 0, s.x);
    atomicAdd(dp + 1, s.y);
    atomicAdd(dp + 2, s.z);
    atomicAdd(dp + 3, s.w);
}

// ---- x -> xT bf16 [B][128][4096] ----
__global__ __launch_bounds__(256) void transpose_x(const float* __restrict__ x,
                                                   unsigned short* __restrict__ xTb) {
    __shared__ float tile[64][65];
    const int b = blockIdx.z, m0 = blockIdx.x * 64, n0 = blockIdx.y * 64;
    const int t = threadIdx.x;
    const int c = t & 63, r4 = t >> 6;
    const float* xb = x + (size_t)b * NC;
#pragma unroll
    for (int i = 0; i < 16; ++i) {
        int r = i * 4 + r4;
        tile[r][c] = xb[(size_t)(m0 + r) * CF + n0 + c];
    }
    __syncthreads();
    unsigned short* xo = xTb + (size_t)b * NC + (size_t)n0 * NN + m0;
#pragma unroll
    for (int i = 0; i < 16; ++i) {
        int r = i * 4 + r4;
        xo[(size_t)r * NN + c] = f2b(tile[c][r]);
    }
}

__global__ __launch_bounds__(256) void wt_kernel(const float* __restrict__ W,
                                                 float* __restrict__ Wt) {
    const int idx = blockIdx.x * 256 + threadIdx.x;  // < 128*384
    const int o = idx / 384;
    const int f = idx % 384;
    Wt[f * 128 + o] = W[idx];
}

// ---- MFMA cheb GEMM: acc[m,n] = sum_k adj[m,k]*z[k,n] over bf16, fp32 epilogue ----
// BM=32, BN=128 (all cols), BK=64. 256 thr / 4 waves; wave w: n-tiles {2w,2w+1}, m-tiles {0,1}.
// MODE 1: Z1 = lr*(deg*x - acc) - x        (writes Zflat chunk1 fp32 + z1Tb bf16 transposed)
// MODE 2: Z2 = 2*(lr*(deg*z1 - acc) - z1) - x   (writes Zflat chunk2 fp32)
// STAGE 0: A from fp32 adj (inline cvt). STAGE 1: A from pre-cast bf16 adjB.
template <int MODE, int STAGE>
__global__ __launch_bounds__(256, 2) void mfma_cheb(
    const void* __restrict__ Aglob,
    const unsigned short* __restrict__ Bt,   // bf16 zT [B][128][4096]
    const float* __restrict__ deg,
    const float* __restrict__ x,
    float* __restrict__ Zflat,
    unsigned short* __restrict__ z1Tb)
{
    const int t = threadIdx.x;
    const int wv = t >> 6, lane = t & 63, q = lane >> 4, l16 = lane & 15;
    const int m0 = blockIdx.x * 32;
    const int b = blockIdx.y;

    __shared__ __align__(16) short lds[2][2048];   // 2 x (32 rows x 64 k) bf16

    // staging lane mapping: row sr (0..31), LDS slot sg0 = t&7, fetches global granule sg
    const int sr = t >> 3;
    const int sg0 = t & 7;
    const int sg = sg0 ^ (sr & 7);                 // XOR swizzle (2-way banks on frag read)

    const float* apf = nullptr;
    const unsigned short* apb = nullptr;
    if (STAGE == 0)
        apf = (const float*)Aglob + (size_t)b * NN * NN + (size_t)(m0 + sr) * NN + sg * 8;
    else
        apb = (const unsigned short*)Aglob + (size_t)b * NN * NN + (size_t)(m0 + sr) * NN + sg * 8;

    // B pointers: frag needs zT[n][k0 + kh*32 + q*8 + j]
    const unsigned short* bp[2];
#pragma unroll
    for (int niw = 0; niw < 2; ++niw) {
        const int n = wv * 32 + niw * 16 + l16;
        bp[niw] = Bt + (size_t)b * NC + (size_t)n * NN + q * 8;
    }

    f32x4 acc[2][2];
#pragma unroll
    for (int i = 0; i < 2; ++i)
#pragma unroll
        for (int j = 0; j < 2; ++j) acc[i][j] = (f32x4)0.f;

    const int ldsw = sr * 64 + sg0 * 8;  // short index for staging write

    // ---- prologue: stage k0=0 into buf0, prefetch B(0) ----
    float4 v0, v1; bf16x8 rawb;
    if (STAGE == 0) {
        v0 = *(const float4*)(apf + 0);
        v1 = *(const float4*)(apf + 4);
        union { bf16x8 v; unsigned short u[8]; } tmp;
        tmp.u[0] = f2b(v0.x); tmp.u[1] = f2b(v0.y); tmp.u[2] = f2b(v0.z); tmp.u[3] = f2b(v0.w);
        tmp.u[4] = f2b(v1.x); tmp.u[5] = f2b(v1.y); tmp.u[6] = f2b(v1.z); tmp.u[7] = f2b(v1.w);
        *(bf16x8*)&lds[0][ldsw] = tmp.v;
    } else {
        rawb = *(const bf16x8*)(apb + 0);
        *(bf16x8*)&lds[0][ldsw] = rawb;
    }
    bf16x8 bf_cur[2][2];
#pragma unroll
    for (int niw = 0; niw < 2; ++niw)
#pragma unroll
        for (int kh = 0; kh < 2; ++kh)
            bf_cur[niw][kh] = *(const bf16x8*)(bp[niw] + kh * 32);
    __syncthreads();

    // ---- main K loop: 64 steps of BK=64, A dbuf, B reg-prefetch ----
    for (int s = 0; s < 64; ++s) {
        const int cur = s & 1;
        const int kn = (s + 1) * 64;
        // issue next A raw loads early (global latency overlaps MFMAs)
        if (s < 63) {
            if (STAGE == 0) {
                v0 = *(const float4*)(apf + kn);
                v1 = *(const float4*)(apf + kn + 4);
            } else {
                rawb = *(const bf16x8*)(apb + kn);
            }
        }
        bf16x8 bf_nxt[2][2];
        if (s < 63) {
#pragma unroll
            for (int niw = 0; niw < 2; ++niw)
#pragma unroll
                for (int kh = 0; kh < 2; ++kh)
                    bf_nxt[niw][kh] = *(const bf16x8*)(bp[niw] + kn + kh * 32);
        }
        // A fragments from LDS (swizzled)
        bf16x8 af[2][2];
#pragma unroll
        for (int mi = 0; mi < 2; ++mi) {
            const int mloc = mi * 16 + l16;
#pragma unroll
            for (int kh = 0; kh < 2; ++kh) {
                const int slot = (kh * 4 + q) ^ (l16 & 7);
                af[mi][kh] = *(const bf16x8*)&lds[cur][mloc * 64 + slot * 8];
            }
        }
#pragma unroll
        for (int kh = 0; kh < 2; ++kh)
#pragma unroll
            for (int mi = 0; mi < 2; ++mi)
#pragma unroll
                for (int niw = 0; niw < 2; ++niw)
                    acc[mi][niw] = __builtin_amdgcn_mfma_f32_16x16x32_bf16(
                        af[mi][kh], bf_cur[niw][kh], acc[mi][niw], 0, 0, 0);
        // write next A tile into other buffer (after all reads of it finished last iter)
        if (s < 63) {
            if (STAGE == 0) {
                union { bf16x8 v; unsigned short u[8]; } tmp;
                tmp.u[0] = f2b(v0.x); tmp.u[1] = f2b(v0.y); tmp.u[2] = f2b(v0.z); tmp.u[3] = f2b(v0.w);
                tmp.u[4] = f2b(v1.x); tmp.u[5] = f2b(v1.y); tmp.u[6] = f2b(v1.z); tmp.u[7] = f2b(v1.w);
                *(bf16x8*)&lds[cur ^ 1][ldsw] = tmp.v;
            } else {
                *(bf16x8*)&lds[cur ^ 1][ldsw] = rawb;
            }
        }
        __syncthreads();
#pragma unroll
        for (int niw = 0; niw < 2; ++niw)
#pragma unroll
            for (int kh = 0; kh < 2; ++kh)
                bf_cur[niw][kh] = bf_nxt[niw][kh];
    }

    // ---- epilogue (fp32) ----
    const float* xb = x + (size_t)b * NC;
    const float* degb = deg + b * NN;
    float* Zf1 = Zflat + (size_t)b * NC3 + NC;
    float* Zf2 = Zflat + (size_t)b * NC3 + 2 * NC;

#pragma unroll
    for (int mi = 0; mi < 2; ++mi) {
        const int mb = m0 + mi * 16 + q * 4;
        const f32x4 dv = *(const f32x4*)(degb + mb);
#pragma unroll
        for (int niw = 0; niw < 2; ++niw) {
            const int n = wv * 32 + niw * 16 + l16;
            const f32x4 a = acc[mi][niw];
            float xv[4];
#pragma unroll
            for (int r = 0; r < 4; ++r) xv[r] = xb[(size_t)(mb + r) * CF + n];
            if (MODE == 1) {
                float z[4];
#pragma unroll
                for (int r = 0; r < 4; ++r) z[r] = LRC * (dv[r] * xv[r] - a[r]) - xv[r];
#pragma unroll
                for (int r = 0; r < 4; ++r) Zf1[(size_t)(mb + r) * CF + n] = z[r];
                ushort4 o;
                o.x = f2b(z[0]); o.y = f2b(z[1]); o.z = f2b(z[2]); o.w = f2b(z[3]);
                *(ushort4*)&z1Tb[(size_t)b * NC + (size_t)n * NN + mb] = o;
            } else {
                float z1r[4];
#pragma unroll
                for (int r = 0; r < 4; ++r) z1r[r] = Zf1[(size_t)(mb + r) * CF + n];
#pragma unroll
                for (int r = 0; r < 4; ++r) {
                    const float c1 = LRC * (dv[r] * z1r[r] - a[r]) - z1r[r];
                    Zf2[(size_t)(mb + r) * CF + n] = 2.f * c1 - xv[r];
                }
            }
        }
    }
}

// ---- final fp32 GEMM over the scrambled view: out[m][o] = sum_f Zflat[m*384+f]*Wt[f][o] ----
__global__ __launch_bounds__(256) void gemm_final(const float* __restrict__ Zflat,
                                                  const float* __restrict__ Wt,
                                                  float* __restrict__ out) {
    const int b = blockIdx.z;
    const float* Ab = Zflat + (size_t)b * NC3;
    float* Cb = out + (size_t)b * NC;

    const int t = threadIdx.x;
    const int tx = t & 15, ty = t >> 4;
    const int m0 = blockIdx.y * 64, n0 = blockIdx.x * 64;

    __shared__ float As[16][68];
    __shared__ float Bs[16][64];

    const int arow = t >> 2;
    const int ak4 = (t & 3) << 2;
    const int bk = t >> 4;
    const int bn4 = (t & 15) << 2;

    float4 acc[4];
    acc[0] = acc[1] = acc[2] = acc[3] = make_float4(0.f, 0.f, 0.f, 0.f);

    const float* aptr = Ab + (size_t)(m0 + arow) * 384 + ak4;
    const float* bptr = Wt + (size_t)bk * 128 + n0 + bn4;

    float4 av = *(const float4*)aptr;
    float4 bv = *(const float4*)bptr;

    for (int k0 = 0; k0 < 384; k0 += 16) {
        __syncthreads();
        As[ak4 + 0][arow] = av.x;
        As[ak4 + 1][arow] = av.y;
        As[ak4 + 2][arow] = av.z;
        As[ak4 + 3][arow] = av.w;
        *(float4*)&Bs[bk][bn4] = bv;
        __syncthreads();
        if (k0 + 16 < 384) {
            av = *(const float4*)(aptr + k0 + 16);
            bv = *(const float4*)(bptr + (size_t)(k0 + 16) * 128);
        }
#pragma unroll
        for (int kk = 0; kk < 16; ++kk) {
            const float4 a = *(const float4*)&As[kk][ty << 2];
            const float4 bb = *(const float4*)&Bs[kk][tx << 2];
            acc[0].x += a.x * bb.x; acc[0].y += a.x * bb.y; acc[0].z += a.x * bb.z; acc[0].w += a.x * bb.w;
            acc[1].x += a.y * bb.x; acc[1].y += a.y * bb.y; acc[1].z += a.y * bb.z; acc[1].w += a.y * bb.w;
            acc[2].x += a.z * bb.x; acc[2].y += a.z * bb.y; acc[2].z += a.z * bb.z; acc[2].w += a.z * bb.w;
            acc[3].x += a.w * bb.x; acc[3].y += a.w * bb.y; acc[3].z += a.w * bb.z; acc[3].w += a.w * bb.w;
        }
    }

    const int ncol = n0 + (tx << 2);
#pragma unroll
    for (int i = 0; i < 4; ++i) {
        const int m = m0 + (ty << 2) + i;
        *(float4*)&Cb[(size_t)m * 128 + ncol] = acc[i];
    }
}

extern "C" void kernel_launch(void* const* d_in, const int* in_sizes, int n_in,
                              void* d_out, int out_size, void* d_ws, size_t ws_size,
                              hipStream_t stream) {
    const float* x   = (const float*)d_in[0];   // [4, 4096, 128]
    const float* adj = (const float*)d_in[1];   // [4, 4096, 4096]
    const float* W   = (const float*)d_in[2];   // [128, 384]
    float* out = (float*)d_out;

    char* ws = (char*)d_ws;
    float* Zflat         = (float*)ws;                                  // 25,165,824 B
    unsigned short* xTb  = (unsigned short*)(ws + 25165824);            //  4,194,304 B
    unsigned short* z1Tb = (unsigned short*)(ws + 29360128);            //  4,194,304 B
    float* deg           = (float*)(ws + 33554432);                     //     65,536 B
    float* Wt            = (float*)(ws + 33619968);                     //    196,608 B
    unsigned short* adjB = (unsigned short*)(ws + 33816576);            // 134,217,728 B (optional)
    const bool use_cast = ws_size >= (size_t)33816576 + 134217728ull;

    hipMemsetAsync(deg, 0, 4 * NN * sizeof(float), stream);
    if (use_cast)
        prep_cast<<<dim3(4, 16, 4), 256, 0, stream>>>(adj, adjB, deg);
    else
        degree_kernel<<<dim3(4, 16, 4), 256, 0, stream>>>(adj, deg);

    transpose_x<<<dim3(64, 2, 4), 256, 0, stream>>>(x, xTb);
    wt_kernel<<<192, 256, 0, stream>>>(W, Wt);

    for (int b = 0; b < 4; ++b)
        hipMemcpyAsync(Zflat + (size_t)b * NC3, x + (size_t)b * NC,
                       NC * sizeof(float), hipMemcpyDeviceToDevice, stream);

    if (use_cast) {
        mfma_cheb<1, 1><<<dim3(128, 4), 256, 0, stream>>>(adjB, xTb, deg, x, Zflat, z1Tb);
        mfma_cheb<2, 1><<<dim3(128, 4), 256, 0, stream>>>(adjB, z1Tb, deg, x, Zflat, z1Tb);
    } else {
        mfma_cheb<1, 0><<<dim3(128, 4), 256, 0, stream>>>(adj, xTb, deg, x, Zflat, z1Tb);
        mfma_cheb<2, 0><<<dim3(128, 4), 256, 0, stream>>>(adj, z1Tb, deg, x, Zflat, z1Tb);
    }

    gemm_final<<<dim3(2, 64, 4), 256, 0, stream>>>(Zflat, Wt, out);
}

// Round 4
// 511.472 us; speedup vs baseline: 1.7420x; 1.1477x over previous
//
#include <hip/hip_runtime.h>

// ChebConv B=4, N=4096, C=128, K=3 fp32.
// Round 4 = Round 3 structure with the gemm_final scramble FIXED:
//   view row m of [4096x384] = flat[m*384 .. m*384+383] over the CONTIGUOUS
//   [3][4096][128] stack (crosses chunk boundaries at m=1365/2730) — NOT
//   [x[m]|z1[m]|z2[m]]. aload now computes chunk = (m*384+k)>>19, rem&524287.
// Everything else identical to round 3:
//   BM=128 x BN=128 x BK=64 MFMA GEMM, 4 waves, 4x4 acc/wave, both operands
//   LDS-staged w/ granule-XOR swizzle, split-K=4 (512 blocks), fp32 partials,
//   fused reduce/epilogue kernels, prep_cast (degree + adj->bf16 one pass).
// ws: adjB 134.2MB | Cpart 33.6MB | Zf 16.8MB | xTb 4MB | z1Tb 4MB | deg | Wt

#define NN 4096
#define CF 128
#define NC (NN * CF)
#define LRC 0.9999995f

typedef __attribute__((ext_vector_type(8))) short bf16x8;
typedef __attribute__((ext_vector_type(4))) float f32x4;

__device__ __forceinline__ unsigned short f2b(float f) {
    unsigned u = __float_as_uint(f);
    return (unsigned short)((u + 0x7FFFu + ((u >> 16) & 1u)) >> 16);  // RNE
}

// ---- one fp32 pass over adj: exact degree + bf16 cast ----
__global__ __launch_bounds__(256) void prep_cast(const float* __restrict__ adj,
                                                 unsigned short* __restrict__ adjB,
                                                 float* __restrict__ deg) {
    const int b = blockIdx.z;
    const size_t base = (size_t)b * NN * NN;
    const int n0 = blockIdx.x * 1024;
    const int m0 = blockIdx.y * 256;
    const int t = threadIdx.x;
    float4 s = make_float4(0.f, 0.f, 0.f, 0.f);
    const size_t col = (size_t)(n0 + t * 4);
    for (int m = 0; m < 256; ++m) {
        const size_t idx = base + (size_t)(m0 + m) * NN + col;
        const float4 v = *(const float4*)&adj[idx];
        s.x += v.x; s.y += v.y; s.z += v.z; s.w += v.w;
        ushort4 o;
        o.x = f2b(v.x); o.y = f2b(v.y); o.z = f2b(v.z); o.w = f2b(v.w);
        *(ushort4*)&adjB[idx] = o;
    }
    float* dp = deg + b * NN + n0 + t * 4;
    atomicAdd(dp + 0, s.x);
    atomicAdd(dp + 1, s.y);
    atomicAdd(dp + 2, s.z);
    atomicAdd(dp + 3, s.w);
}

// ---- x -> xT bf16 [B][128 feat][4096 node] ----
__global__ __launch_bounds__(256) void transpose_x(const float* __restrict__ x,
                                                   unsigned short* __restrict__ xTb) {
    __shared__ float tile[64][65];
    const int b = blockIdx.z, m0 = blockIdx.x * 64, n0 = blockIdx.y * 64;
    const int t = threadIdx.x;
    const int c = t & 63, r4 = t >> 6;
    const float* xb = x + (size_t)b * NC;
#pragma unroll
    for (int i = 0; i < 16; ++i) {
        int r = i * 4 + r4;
        tile[r][c] = xb[(size_t)(m0 + r) * CF + n0 + c];
    }
    __syncthreads();
    unsigned short* xo = xTb + (size_t)b * NC + (size_t)n0 * NN + m0;
#pragma unroll
    for (int i = 0; i < 16; ++i) {
        int r = i * 4 + r4;
        xo[(size_t)r * NN + c] = f2b(tile[c][r]);
    }
}

__global__ __launch_bounds__(256) void wt_kernel(const float* __restrict__ W,
                                                 float* __restrict__ Wt) {
    const int idx = blockIdx.x * 256 + threadIdx.x;  // < 128*384
    const int o = idx / 384;
    const int f = idx % 384;
    Wt[f * 128 + o] = W[idx];
}

// ---- split-K MFMA GEMM: Cpart[b][kc] = adjB[m, kc-chunk] @ z[kc-chunk, n] ----
__global__ __launch_bounds__(256, 2) void mfma_part(
    const unsigned short* __restrict__ adjB,
    const unsigned short* __restrict__ Bt,   // bf16 zT [B][128][4096]
    float* __restrict__ Cpart)
{
    const int t = threadIdx.x;
    const int w = t >> 6, lane = t & 63, q = lane >> 4, l16 = lane & 15;
    const int wm = w & 1, wn = w >> 1;
    const int m0 = blockIdx.x * 128;
    const int kc = blockIdx.y;
    const int b  = blockIdx.z;

    __shared__ __align__(16) short As[8192];   // 16 KB
    __shared__ __align__(16) short Bs[8192];   // 16 KB

    const int g  = t & 7;          // k-granule (8 shorts = 16 B)
    const int r0 = t >> 3;         // row 0..31 (+32i)

    const unsigned short* ap = adjB + (size_t)b * NN * NN + (size_t)kc * 1024 + g * 8;
    const unsigned short* bp = Bt   + (size_t)b * NC      + (size_t)kc * 1024 + g * 8;

    f32x4 acc[4][4];
#pragma unroll
    for (int i = 0; i < 4; ++i)
#pragma unroll
        for (int j = 0; j < 4; ++j) acc[i][j] = (f32x4)0.f;

    bf16x8 ar[4], br[4];
#pragma unroll
    for (int i = 0; i < 4; ++i) {
        const int r = r0 + i * 32;
        ar[i] = *(const bf16x8*)(ap + (size_t)(m0 + r) * NN);
        br[i] = *(const bf16x8*)(bp + (size_t)r * NN);
    }

    for (int it = 0; it < 16; ++it) {
        __syncthreads();   // previous iteration's frag reads complete
#pragma unroll
        for (int i = 0; i < 4; ++i) {
            const int r = r0 + i * 32;
            const int slot = (g ^ (r & 7)) << 3;
            *(bf16x8*)&As[r * 64 + slot] = ar[i];
            *(bf16x8*)&Bs[r * 64 + slot] = br[i];
        }
        __syncthreads();
        if (it < 15) {
            const int kof = (it + 1) * 64;
#pragma unroll
            for (int i = 0; i < 4; ++i) {
                const int r = r0 + i * 32;
                ar[i] = *(const bf16x8*)(ap + (size_t)(m0 + r) * NN + kof);
                br[i] = *(const bf16x8*)(bp + (size_t)r * NN + kof);
            }
        }
#pragma unroll
        for (int kh = 0; kh < 2; ++kh) {
            bf16x8 af[4], bf[4];
#pragma unroll
            for (int i = 0; i < 4; ++i) {
                const int ml = wm * 64 + i * 16 + l16;
                af[i] = *(const bf16x8*)&As[ml * 64 + ((((kh << 2) + q) ^ (ml & 7)) << 3)];
                const int nl = wn * 64 + i * 16 + l16;
                bf[i] = *(const bf16x8*)&Bs[nl * 64 + ((((kh << 2) + q) ^ (nl & 7)) << 3)];
            }
#pragma unroll
            for (int i = 0; i < 4; ++i)
#pragma unroll
                for (int j = 0; j < 4; ++j)
                    acc[i][j] = __builtin_amdgcn_mfma_f32_16x16x32_bf16(
                        af[i], bf[j], acc[i][j], 0, 0, 0);
        }
    }

    // store fp32 partials: C/D layout col=l16, row=q*4+reg
    float* Cb = Cpart + (size_t)(b * 4 + kc) * NC;
#pragma unroll
    for (int i = 0; i < 4; ++i) {
        const int mrow = m0 + wm * 64 + i * 16 + q * 4;
#pragma unroll
        for (int j = 0; j < 4; ++j) {
            const int n = wn * 64 + j * 16 + l16;
#pragma unroll
            for (int r = 0; r < 4; ++r)
                Cb[(size_t)(mrow + r) * CF + n] = acc[i][j][r];
        }
    }
}

// ---- reduce partials + Z1 epilogue + transposed bf16 z1 ----
__global__ __launch_bounds__(256) void reduce_z1(const float* __restrict__ Cpart,
                                                 const float* __restrict__ x,
                                                 const float* __restrict__ deg,
                                                 float* __restrict__ Zf,
                                                 unsigned short* __restrict__ z1Tb) {
    __shared__ unsigned short sh[64][68];
    const int b = blockIdx.z, m0 = blockIdx.x * 64, n0 = blockIdx.y * 64;
    const int t = threadIdx.x;
    const int r0 = (t >> 4) * 4, c0 = (t & 15) * 4;
    const float* degb = deg + b * NN;
    const float* xb = x + (size_t)b * NC;
    float* Zf1 = Zf + (size_t)b * 2 * NC;
#pragma unroll
    for (int rr = 0; rr < 4; ++rr) {
        const int m = m0 + r0 + rr;
        f32x4 s = (f32x4)0.f;
#pragma unroll
        for (int kc = 0; kc < 4; ++kc)
            s += *(const f32x4*)&Cpart[(size_t)(b * 4 + kc) * NC + (size_t)m * CF + n0 + c0];
        const f32x4 xv = *(const f32x4*)&xb[(size_t)m * CF + n0 + c0];
        const float d = degb[m];
        f32x4 z;
#pragma unroll
        for (int cc = 0; cc < 4; ++cc) z[cc] = LRC * (d * xv[cc] - s[cc]) - xv[cc];
        *(f32x4*)&Zf1[(size_t)m * CF + n0 + c0] = z;
#pragma unroll
        for (int cc = 0; cc < 4; ++cc) sh[c0 + cc][r0 + rr] = f2b(z[cc]);
    }
    __syncthreads();
    unsigned short* zo = z1Tb + (size_t)b * NC + (size_t)n0 * NN + m0;
    const int nl = t >> 2;
#pragma unroll
    for (int i = 0; i < 4; ++i) {
        const int ml = ((t & 3) + i * 4) * 4;
        ushort4 v;
        v.x = sh[nl][ml]; v.y = sh[nl][ml + 1]; v.z = sh[nl][ml + 2]; v.w = sh[nl][ml + 3];
        *(ushort4*)&zo[(size_t)nl * NN + ml] = v;
    }
}

// ---- reduce partials + Z2 epilogue ----
__global__ __launch_bounds__(256) void reduce_z2(const float* __restrict__ Cpart,
                                                 const float* __restrict__ x,
                                                 const float* __restrict__ deg,
                                                 float* __restrict__ Zf) {
    const size_t gidx = (size_t)blockIdx.x * 256 + threadIdx.x;   // over 4*NC/4 vec4s
    const int b = (int)(gidx / (NC / 4));
    const size_t rem = gidx % (NC / 4);
    const int m = (int)(rem / (CF / 4));
    const int c0 = (int)(rem % (CF / 4)) * 4;
    f32x4 s = (f32x4)0.f;
#pragma unroll
    for (int kc = 0; kc < 4; ++kc)
        s += *(const f32x4*)&Cpart[(size_t)(b * 4 + kc) * NC + (size_t)m * CF + c0];
    const f32x4 xv = *(const f32x4*)&x[(size_t)b * NC + (size_t)m * CF + c0];
    const f32x4 z1 = *(const f32x4*)&Zf[(size_t)b * 2 * NC + (size_t)m * CF + c0];
    const float d = deg[b * NN + m];
    f32x4 z;
#pragma unroll
    for (int cc = 0; cc < 4; ++cc)
        z[cc] = 2.f * (LRC * (d * z1[cc] - s[cc]) - z1[cc]) - xv[cc];
    *(f32x4*)&Zf[(size_t)b * 2 * NC + NC + (size_t)m * CF + c0] = z;
}

// ---- final fp32 GEMM over the TRUE scrambled view ----
// view row m, col f  ->  flat index G = m*384+f over [x | z1 | z2] (each 2^19 elems):
//   chunk = G>>19, rem = G & (2^19-1); float4 at f%4==0 never crosses a boundary.
__global__ __launch_bounds__(256) void gemm_final(const float* __restrict__ x,
                                                  const float* __restrict__ Zf,
                                                  const float* __restrict__ Wt,
                                                  float* __restrict__ out) {
    const int b = blockIdx.z;
    float* Cb = out + (size_t)b * NC;

    const int t = threadIdx.x;
    const int tx = t & 15, ty = t >> 4;
    const int m0 = blockIdx.y * 64, n0 = blockIdx.x * 64;

    __shared__ float Asm[16][68];
    __shared__ float Bsm[16][64];

    const int arow = t >> 2;
    const int ak4 = (t & 3) << 2;
    const int bk = t >> 4;
    const int bn4 = (t & 15) << 2;

    const float* xb = x + (size_t)b * NC;

    float4 acc[4];
    acc[0] = acc[1] = acc[2] = acc[3] = make_float4(0.f, 0.f, 0.f, 0.f);

    const float* bptr = Wt + (size_t)bk * 128 + n0 + bn4;

    auto aload = [&](int k) -> float4 {
        const unsigned G = (unsigned)(m0 + arow) * 384u + (unsigned)k;
        const int chunk = (int)(G >> 19);
        const unsigned rem = G & 524287u;
        const float* src = (chunk == 0) ? xb : (Zf + (size_t)(b * 2 + (chunk - 1)) * NC);
        return *(const float4*)&src[rem];
    };

    float4 av = aload(ak4);
    float4 bv = *(const float4*)bptr;

    for (int k0 = 0; k0 < 384; k0 += 16) {
        __syncthreads();
        Asm[ak4 + 0][arow] = av.x;
        Asm[ak4 + 1][arow] = av.y;
        Asm[ak4 + 2][arow] = av.z;
        Asm[ak4 + 3][arow] = av.w;
        *(float4*)&Bsm[bk][bn4] = bv;
        __syncthreads();
        if (k0 + 16 < 384) {
            av = aload(k0 + 16 + ak4);
            bv = *(const float4*)(bptr + (size_t)(k0 + 16) * 128);
        }
#pragma unroll
        for (int kk = 0; kk < 16; ++kk) {
            const float4 a = *(const float4*)&Asm[kk][ty << 2];
            const float4 bb = *(const float4*)&Bsm[kk][tx << 2];
            acc[0].x += a.x * bb.x; acc[0].y += a.x * bb.y; acc[0].z += a.x * bb.z; acc[0].w += a.x * bb.w;
            acc[1].x += a.y * bb.x; acc[1].y += a.y * bb.y; acc[1].z += a.y * bb.z; acc[1].w += a.y * bb.w;
            acc[2].x += a.z * bb.x; acc[2].y += a.z * bb.y; acc[2].z += a.z * bb.z; acc[2].w += a.z * bb.w;
            acc[3].x += a.w * bb.x; acc[3].y += a.w * bb.y; acc[3].z += a.w * bb.z; acc[3].w += a.w * bb.w;
        }
    }

    const int ncol = n0 + (tx << 2);
#pragma unroll
    for (int i = 0; i < 4; ++i) {
        const int m = m0 + (ty << 2) + i;
        *(float4*)&Cb[(size_t)m * 128 + ncol] = acc[i];
    }
}

extern "C" void kernel_launch(void* const* d_in, const int* in_sizes, int n_in,
                              void* d_out, int out_size, void* d_ws, size_t ws_size,
                              hipStream_t stream) {
    const float* x   = (const float*)d_in[0];   // [4, 4096, 128]
    const float* adj = (const float*)d_in[1];   // [4, 4096, 4096]
    const float* W   = (const float*)d_in[2];   // [128, 384]
    float* out = (float*)d_out;

    char* ws = (char*)d_ws;
    unsigned short* adjB = (unsigned short*)ws;                     // 134,217,728 B
    float* Cpart         = (float*)(ws + 134217728u);               //  33,554,432 B
    float* Zf            = (float*)(ws + 167772160u);               //  16,777,216 B  [b][z1,z2][4096][128]
    unsigned short* xTb  = (unsigned short*)(ws + 184549376u);      //   4,194,304 B
    unsigned short* z1Tb = (unsigned short*)(ws + 188743680u);      //   4,194,304 B
    float* deg           = (float*)(ws + 192937984u);               //      65,536 B
    float* Wt            = (float*)(ws + 193003520u);               //     196,608 B

    hipMemsetAsync(deg, 0, 4 * NN * sizeof(float), stream);
    prep_cast<<<dim3(4, 16, 4), 256, 0, stream>>>(adj, adjB, deg);
    transpose_x<<<dim3(64, 2, 4), 256, 0, stream>>>(x, xTb);
    wt_kernel<<<192, 256, 0, stream>>>(W, Wt);

    // Z1 = lr*(deg*x - adj@x) - x
    mfma_part<<<dim3(32, 4, 4), 256, 0, stream>>>(adjB, xTb, Cpart);
    reduce_z1<<<dim3(64, 2, 4), 256, 0, stream>>>(Cpart, x, deg, Zf, z1Tb);

    // Z2 = 2*(lr*(deg*z1 - adj@z1) - z1) - x
    mfma_part<<<dim3(32, 4, 4), 256, 0, stream>>>(adjB, z1Tb, Cpart);
    reduce_z2<<<2048, 256, 0, stream>>>(Cpart, x, deg, Zf);

    // out = [x | z1 | z2] (scrambled view) @ Wt
    gemm_final<<<dim3(2, 64, 4), 256, 0, stream>>>(x, Zf, Wt, out);
}